// Round 11
// baseline (2307.046 us; speedup 1.0000x reference)
//
#include <hip/hip_runtime.h>

typedef float f32x2 __attribute__((ext_vector_type(2)));

constexpr int H=100, NIN=10, OUTN=10, NB=64, T=2048;
constexpr int RING=16, RM=RING-1, CHK=4;   // LDS rings 16 steps, 4-step chunks

#define PKF(acc,w,p) asm("v_pk_fma_f32 %0, %1, %2, %0":"+v"(acc):"v"(w),"v"(p))

#define REP25(X) X(0) X(1) X(2) X(3) X(4) X(5) X(6) X(7) X(8) X(9) \
  X(10) X(11) X(12) X(13) X(14) X(15) X(16) X(17) X(18) X(19) \
  X(20) X(21) X(22) X(23) X(24)

// Weights live in AGPRs — the one register class with no other users, which
// the allocator can neither rematerialize nor profitably spill. R10 proved
// the "=a" tie allocates cleanly; it also proved VOP3P can't read AGPRs, so
// each use pays an explicit v_accvgpr_read_b32 (volatile: never hoisted into
// a VGPR live range the RA would spill). 150 VALU/step/half vs ~75 today,
// but ZERO per-step weight memory traffic — rounds 1-9 were pinned at the
// ~34.5 TB/s L2 ceiling re-reading 47 GB of weights (the 1.14-1.45 ms wall).
#define DECLW1(i) float Wax##i,Way##i,Wbx##i,Wby##i;
#define LOADW1(i) { float4 w_=*(const float4*)(wrow_+4*(i)); \
  asm("" : "=a"(Wax##i) : "0"(w_.x)); asm("" : "=a"(Way##i) : "0"(w_.y)); \
  asm("" : "=a"(Wbx##i) : "0"(w_.z)); asm("" : "=a"(Wby##i) : "0"(w_.w)); }
#define DOT1(i) { float4 hv_=h4_[(i)]; f32x2 w0_,w1_,p0_,p1_; \
  asm volatile("v_accvgpr_read_b32 %0, %1":"=v"(w0_.x):"a"(Wax##i)); \
  asm volatile("v_accvgpr_read_b32 %0, %1":"=v"(w0_.y):"a"(Way##i)); \
  asm volatile("v_accvgpr_read_b32 %0, %1":"=v"(w1_.x):"a"(Wbx##i)); \
  asm volatile("v_accvgpr_read_b32 %0, %1":"=v"(w1_.y):"a"(Wby##i)); \
  p0_.x=hv_.x; p0_.y=hv_.y; p1_.x=hv_.z; p1_.y=hv_.w; \
  PKF(a0_,w0_,p0_); PKF(a1_,w1_,p1_); }

__device__ __forceinline__ float ftanh(float x){
  float e=__expf(x+x); return 1.0f - 2.0f/(e+1.0f);
}

__device__ __forceinline__ void waitGE(int* f,int tgt){
  if (tgt<=0) return;
  while (__hip_atomic_load(f,__ATOMIC_RELAXED,__HIP_MEMORY_SCOPE_WORKGROUP)<tgt)
    __builtin_amdgcn_s_sleep(1);
  (void)__hip_atomic_load(f,__ATOMIC_ACQUIRE,__HIP_MEMORY_SCOPE_WORKGROUP);
}
// single-load acquire poll for the serial-path partner sync
__device__ __forceinline__ void waitGEa(int* f,int tgt){
  if (tgt<=0) return;
  while (__hip_atomic_load(f,__ATOMIC_ACQUIRE,__HIP_MEMORY_SCOPE_WORKGROUP)<tgt)
    __builtin_amdgcn_s_sleep(1);
}
__device__ __forceinline__ void pub(int* f,int v,int lane){
  if (lane==0) __hip_atomic_store(f,v,__ATOMIC_RELEASE,__HIP_MEMORY_SCOPE_WORKGROUP);
}
__device__ __forceinline__ void waitGEg(int* f,int tgt){
  if (tgt<=0) return;
  while (__hip_atomic_load(f,__ATOMIC_RELAXED,__HIP_MEMORY_SCOPE_AGENT)<tgt)
    __builtin_amdgcn_s_sleep(8);
  (void)__hip_atomic_load(f,__ATOMIC_ACQUIRE,__HIP_MEMORY_SCOPE_AGENT);
}
__device__ __forceinline__ void pubg(int* f,int v,int lane){
  if (lane==0) __hip_atomic_store(f,v,__ATOMIC_RELEASE,__HIP_MEMORY_SCOPE_AGENT);
}

// HH half body: one Whh row/lane (AGPR-resident), recurrence
// h[t]=tanh(ihc[t]+row.h[t-1]). Per-step pair sync via sc counters.
#define HH_LOOP(hrL,icL,scS,scP,fpi,fch1,fch2,fci,hfp) \
  for (int m=0;m<T;m+=CHK){ \
    waitGE((fpi),m+CHK); \
    waitGE((fch1),m-(RING-CHK)); \
    if ((fch2)!=nullptr) waitGE((fch2),m-(RING-CHK)); \
    _Pragma("unroll") \
    for (int tt=0;tt<CHK;++tt){ \
      const int t=m+tt; \
      waitGEa((scP),t); \
      const float4* h4_=(const float4*)(hrL)[(t-1)&RM]; \
      f32x2 a0_,a1_; \
      a0_.x=(icL)[t&RM][rc]; a0_.y=0.f; a1_.x=0.f; a1_.y=0.f; \
      REP25(DOT1) \
      const float hn_=ftanh(a0_.x+a0_.y+a1_.x+a1_.y); \
      if (vr){ \
        (hrL)[t&RM][rc]=hn_; \
        if (t==T-1) (hfp)[rc]=hn_; \
      } \
      pub((scS),t+1,lane); \
    } \
    pub((fci),m+CHK,lane); \
  }

// IH half body: ihc_row[t] = bias + row . h_src[t]; throughput stage.
#define IH_LOOP(hsrc,srm,icT,f1,f2,fci,fchS,fpiS) \
  for (int m=0;m<T;m+=CHK){ \
    waitGE((f1),m+CHK); \
    if ((f2)!=nullptr) waitGE((f2),m+CHK); \
    waitGE((fci),m-(RING-CHK)); \
    _Pragma("unroll") \
    for (int tt=0;tt<CHK;++tt){ \
      const int t=m+tt; \
      const float4* h4_=(const float4*)(hsrc)[t&(srm)]; \
      f32x2 a0_,a1_; a0_.x=bs; a0_.y=0.f; a1_.x=0.f; a1_.y=0.f; \
      REP25(DOT1) \
      if (vr) (icT)[t&RM][rc]=a0_.x+a0_.y+a1_.x+a1_.y; \
    } \
    pub((fchS),m+CHK,lane); \
    pub((fpiS),m+CHK,lane); \
  }

// grid 128 = 2 blocks/batch. bt0: layers 0-2 (11 waves); bt1: layers 3-4 + out.
// No __syncthreads in-loop; all pacing via LDS flags, one global h2 boundary.
// Structure byte-identical to round 8 (passed); only weight storage changed.
__global__ __launch_bounds__(704)
__attribute__((amdgpu_waves_per_eu(3,3)))
void rnn5(const float* __restrict__ xg, const float* __restrict__ hprev,
          const float* __restrict__ Wih0, const float* __restrict__ Wih,
          const float* __restrict__ Whh, const float* __restrict__ bih,
          const float* __restrict__ bhh, const float* __restrict__ Wout,
          const float* __restrict__ bout, float* __restrict__ outf,
          float* __restrict__ h2g, int* __restrict__ gflags, int gring)
{
  __shared__ __align__(16) float hr[3][RING][H];   // h rings (3 local layers)
  __shared__ __align__(16) float ic[3][RING][H];   // ihc rings
  __shared__ __align__(16) float h2s[32][H];       // staged h2 (block B)
  __shared__ int flg[32];

  const int tid=threadIdx.x, wv=tid>>6, lane=tid&63;
  const int bt=blockIdx.x>>6, b=blockIdx.x&63;
  const size_t hfB=(size_t)NB*T*OUTN;
  const int Lbase=bt?3:0, NLOC=bt?2:3;

  if (tid<32) flg[tid]=0;
  for (int i=tid;i<NLOC*H;i+=704){
    const int li=i/H, r=i-li*H;
    hr[li][RM][r]=hprev[((size_t)(Lbase+li)*NB+b)*H+r];
  }
  __syncthreads();                                  // the ONLY barrier

  int* gp2=&gflags[b*16+0];
  int* gc2=&gflags[b*16+1];
  float* h2base=h2g+(size_t)b*gring*H;
  const int gm1=gring-1;

  if (bt==0){
    // flags A: 0-5 sc(hh l,half) | 6 pi0 | 7-10 pi1a,b,pi2a,b | 11-16 ci0a..ci2b
    //          17,18 ch0(by IH1a/b) | 19,20 ch1(by IH2a/b) | 21 ch2(copier)
    // waves: w0 HH1a w1 HH1b w2 HH2a w3 HH0a w4 IH1a w5 IH1b
    //        w6 HH2b w7 HH0b w8 IH2a w9 IH2b w10 IH0+h2copy   (SIMD-balanced)
    if (wv<4 || wv==6 || wv==7){
      int hl, half;
      if (wv==3){hl=0;half=0;} else if (wv==7){hl=0;half=1;}
      else if (wv==0){hl=1;half=0;} else if (wv==1){hl=1;half=1;}
      else if (wv==2){hl=2;half=0;} else {hl=2;half=1;}
      const int r=half*64+lane; const bool vr=r<H; const int rc=vr?r:96;
      REP25(DECLW1)
      const float* wrow_=Whh+(size_t)hl*H*H+(size_t)rc*H;
      REP25(LOADW1)
      int* scS=&flg[2*hl+half]; int* scP=&flg[2*hl+(half^1)];
      int *fpi,*fch1,*fch2=nullptr,*fci;
      if (hl==0){ fpi=&flg[6];      fch1=&flg[17]; fch2=&flg[18]; fci=&flg[11+half]; }
      else if (hl==1){ fpi=&flg[7+half]; fch1=&flg[19]; fch2=&flg[20]; fci=&flg[13+half]; }
      else          { fpi=&flg[9+half]; fch1=&flg[21];               fci=&flg[15+half]; }
      float* hfp=outf+hfB+((size_t)hl*NB+b)*H;
      HH_LOOP(hr[hl],ic[hl],scS,scP,fpi,fch1,fch2,fci,hfp)
    } else if (wv==4||wv==5||wv==8||wv==9){
      const int tl=(wv<6)?1:2, half=wv&1;
      const int r=half*64+lane; const bool vr=r<H; const int rc=vr?r:96;
      REP25(DECLW1)
      const float* wrow_=Wih+(size_t)(tl-1)*H*H+(size_t)rc*H;
      REP25(LOADW1)
      const float bs=bih[(size_t)tl*H+rc]+bhh[(size_t)tl*H+rc];
      int* f1=&flg[2*(tl-1)]; int* f2=&flg[2*(tl-1)+1];
      int* fci =&flg[(tl==1?13:15)+half];
      int* fchS=&flg[(tl==1?17:19)+half];
      int* fpiS=&flg[(tl==1?7:9)+half];
      IH_LOOP(hr[tl-1],RM,ic[tl],f1,f2,fci,fchS,fpiS)
    } else {
      // ---- IH0 (x->ihc0) + h2 copier (hr[2] -> global ring), light wave ----
      const int r0=2*lane, r1=r0+1; const bool vr=r0<H;
      const int rc0=vr?r0:96, rc1=vr?r1:97; const float mk=vr?1.f:0.f;
      f32x2 XA[5],XB[5];
#pragma unroll
      for (int k=0;k<5;++k){
        f32x2 wa=*(const f32x2*)(Wih0+(size_t)rc0*NIN+2*k);
        f32x2 wb=*(const f32x2*)(Wih0+(size_t)rc1*NIN+2*k);
        XA[k].x=wa.x*mk; XA[k].y=wa.y*mk;
        XB[k].x=wb.x*mk; XB[k].y=wb.y*mk;
      }
      f32x2 bs; bs.x=bih[rc0]+bhh[rc0]; bs.y=bih[rc1]+bhh[rc1];
      const float* xb=xg+(size_t)b*T*NIN;
      f32x2 xc[CHK][5], xn[CHK][5];
#pragma unroll
      for (int tt=0;tt<CHK;++tt)
#pragma unroll
        for (int k=0;k<5;++k) xc[tt][k]=*(const f32x2*)(xb+(size_t)tt*NIN+2*k);
      for (int m=0;m<T;m+=CHK){
        waitGE(&flg[11],m-(RING-CHK));
        waitGE(&flg[12],m-(RING-CHK));
        if (m+CHK<T){
#pragma unroll
          for (int tt=0;tt<CHK;++tt)
#pragma unroll
            for (int k=0;k<5;++k)
              xn[tt][k]=*(const f32x2*)(xb+(size_t)(m+CHK+tt)*NIN+2*k);
        }
#pragma unroll
        for (int tt=0;tt<CHK;++tt){
          const int t=m+tt;
          f32x2 a0,a1; a0.x=bs.x;a0.y=0.f; a1.x=bs.y;a1.y=0.f;
#pragma unroll
          for (int k=0;k<5;++k){ PKF(a0,XA[k],xc[tt][k]); PKF(a1,XB[k],xc[tt][k]); }
          if (vr){
            f32x2 st; st.x=a0.x+a0.y; st.y=a1.x+a1.y;
            *(f32x2*)&ic[0][t&RM][r0]=st;
          }
        }
#pragma unroll
        for (int tt=0;tt<CHK;++tt)
#pragma unroll
          for (int k=0;k<5;++k) xc[tt][k]=xn[tt][k];
        pub(&flg[6],m+CHK,lane);                 // pi0 BEFORE copy-wait
        if (m>=16){                              // copy chunk m-16 (lag D=16)
          const int mc=m-16;
          waitGE(&flg[4],mc+CHK); waitGE(&flg[5],mc+CHK);   // sc2a/b
          waitGEg(gc2,mc+CHK-gring);                         // global ring space
          for (int q=0;q<4;++q){
            const int i=q*64+lane;
            if (i<200){
              const int sl=i/50, rr=2*(i-sl*50);
              f32x2 v=*(const f32x2*)&hr[2][(mc+sl)&RM][rr];
              *(f32x2*)&h2base[(size_t)((mc+sl)&gm1)*H+rr]=v;
            }
          }
          pub(&flg[21],mc+CHK,lane);                         // ch2copy
          if (((mc+CHK)&15)==0) pubg(gp2,mc+CHK,lane);       // 16-step global pub
        }
      }
      for (int mc=T-16;mc<T;mc+=CHK){            // tail: last 4 chunks
        waitGE(&flg[4],mc+CHK); waitGE(&flg[5],mc+CHK);
        waitGEg(gc2,mc+CHK-gring);
        for (int q=0;q<4;++q){
          const int i=q*64+lane;
          if (i<200){
            const int sl=i/50, rr=2*(i-sl*50);
            f32x2 v=*(const f32x2*)&hr[2][(mc+sl)&RM][rr];
            *(f32x2*)&h2base[(size_t)((mc+sl)&gm1)*H+rr]=v;
          }
        }
        pub(&flg[21],mc+CHK,lane);
        if (((mc+CHK)&15)==0) pubg(gp2,mc+CHK,lane);         // last = T
      }
    }
  } else {
    // flags B: 0-3 sc3a,b,sc4a,b | 4-7 pi3a,b,pi4a,b | 8-11 ci3a..ci4b
    //          12,13 ch3(by IH4a/b) | 14 ch4(by OUT) | 15 ph2s | 16,17 ch2sA/B
    // waves: w0 HH4a w1 HH4b w2 HH3a w3 HH3b w4 IH3a w5 IH3b
    //        w6 OUT  w7 STG  w8 IH4a w9 IH4b w10 idle
    if (wv<4){
      const int li=(wv<2)?1:0, half=wv&1, gl=3+li;
      const int r=half*64+lane; const bool vr=r<H; const int rc=vr?r:96;
      REP25(DECLW1)
      const float* wrow_=Whh+(size_t)gl*H*H+(size_t)rc*H;
      REP25(LOADW1)
      int* scS=&flg[2*li+half]; int* scP=&flg[2*li+(half^1)];
      int *fpi=&flg[4+2*li+half], *fch1, *fch2=nullptr, *fci=&flg[8+2*li+half];
      if (li==0){ fch1=&flg[12]; fch2=&flg[13]; }
      else      { fch1=&flg[14]; }
      float* hfp=outf+hfB+((size_t)gl*NB+b)*H;
      HH_LOOP(hr[li],ic[li],scS,scP,fpi,fch1,fch2,fci,hfp)
    } else if (wv==4||wv==5||wv==8||wv==9){
      const int li=(wv<6)?0:1, half=wv&1, gl=3+li;
      const int r=half*64+lane; const bool vr=r<H; const int rc=vr?r:96;
      REP25(DECLW1)
      const float* wrow_=Wih+(size_t)(gl-1)*H*H+(size_t)rc*H;
      REP25(LOADW1)
      const float bs=bih[(size_t)gl*H+rc]+bhh[(size_t)gl*H+rc];
      int *fci=&flg[8+2*li+half], *fpiS=&flg[4+2*li+half];
      if (li==0){
        int* f1=&flg[15]; int* f2=nullptr; int* fchS=&flg[16+half];
        IH_LOOP(h2s,31,ic[li],f1,f2,fci,fchS,fpiS)
      } else {
        int* f1=&flg[0]; int* f2=&flg[1]; int* fchS=&flg[12+half];
        IH_LOOP(hr[0],RM,ic[li],f1,f2,fci,fchS,fpiS)
      }
    } else if (wv==6){
      // ---- OUT: y = Wout.h4 + bout, lanes 0-9 own one row each ----
      const bool vr=lane<OUTN; const int rc=vr?lane:0;
      REP25(DECLW1)
      const float* wrow_=Wout+(size_t)rc*H;
      REP25(LOADW1)
      const float bo=vr?bout[lane]:0.f;
      for (int m=0;m<T;m+=CHK){
        waitGE(&flg[2],m+CHK); waitGE(&flg[3],m+CHK);  // sc4a/b
#pragma unroll
        for (int tt=0;tt<CHK;++tt){
          const int t=m+tt;
          const float4* h4_=(const float4*)hr[1][t&RM];
          f32x2 a0_,a1_; a0_.x=bo; a0_.y=0.f; a1_.x=0.f; a1_.y=0.f;
          REP25(DOT1)
          if (vr) outf[((size_t)b*T+t)*OUTN+lane]=a0_.x+a0_.y+a1_.x+a1_.y;
        }
        pub(&flg[14],m+CHK,lane);
      }
    } else if (wv==7){
      // ---- STG: global h2 ring -> h2s LDS (16-step chunks) ----
      for (int mc=0;mc<T;mc+=16){
        waitGEg(gp2,mc+16);
        waitGE(&flg[16],mc-16);
        waitGE(&flg[17],mc-16);
        for (int q=0;q<13;++q){
          const int i=q*64+lane;
          if (i<800){
            const int sl=i/50, rr=2*(i-sl*50);
            f32x2 v=*(const f32x2*)&h2base[(size_t)((mc+sl)&gm1)*H+rr];
            *(f32x2*)&h2s[(mc+sl)&31][rr]=v;
          }
        }
        pub(&flg[15],mc+16,lane);
        pubg(gc2,mc+16,lane);
      }
    }
    // wv==10: idle wave (keeps both block shapes at 704 threads)
  }
}

extern "C" void kernel_launch(void* const* d_in, const int* in_sizes, int n_in,
                              void* d_out, int out_size, void* d_ws, size_t ws_size,
                              hipStream_t stream){
  int* gflags=(int*)d_ws;                    // 64 batches x 2 flags, poison<0 ok
  float* h2g=(float*)((char*)d_ws+4096);
  int gring=128;
  while (gring>32 && (size_t)4096+(size_t)NB*gring*H*sizeof(float) > ws_size) gring>>=1;
  rnn5<<<dim3(128), dim3(704), 0, stream>>>(
    (const float*)d_in[0], (const float*)d_in[1], (const float*)d_in[2],
    (const float*)d_in[3], (const float*)d_in[4], (const float*)d_in[5],
    (const float*)d_in[6], (const float*)d_in[7], (const float*)d_in[8],
    (float*)d_out, h2g, gflags, gring);
}